// Round 1
// baseline (163.395 us; speedup 1.0000x reference)
//
#include <hip/hip_runtime.h>
#include <math.h>

#define NB 8
#define N_OP 1000
#define N_MA 64
#define IN_SRC 128
#define IN_DST 64
#define DD 128
#define NEG_SLOPE 0.2f

__device__ __forceinline__ float lrelu(float x) { return x >= 0.f ? x : NEG_SLOPE * x; }

__device__ __forceinline__ float wave_sum(float v) {
    for (int off = 32; off; off >>= 1) v += __shfl_xor(v, off, 64);
    return v;
}
__device__ __forceinline__ float wave_max(float v) {
    for (int off = 32; off; off >>= 1) v = fmaxf(v, __shfl_xor(v, off, 64));
    return v;
}

// K1: u[i] = sum_d W_src[i,d]*attn_l[d]  (i in 0..127); c_we = dot(W_edge, attn_l)
__global__ void prep_kernel(const float* __restrict__ W_src, const float* __restrict__ W_edge,
                            const float* __restrict__ attn_l, float* __restrict__ u,
                            float* __restrict__ c_we) {
    int i = threadIdx.x;  // 128 threads
    float acc = 0.f;
    for (int d = 0; d < DD; ++d) acc += W_src[i * DD + d] * attn_l[d];
    u[i] = acc;
    float part = W_edge[i] * attn_l[i];
    part = wave_sum(part);
    __shared__ float red[2];
    if ((i & 63) == 0) red[i >> 6] = part;
    __syncthreads();
    if (i == 0) c_we[0] = red[0] + red[1];
}

// K2: el[row] = dot(h_src[row,:], u), row in 0..B*N_OP. One wave per row.
__global__ void el_kernel(const float* __restrict__ h_src, const float* __restrict__ u,
                          float* __restrict__ el) {
    int row = blockIdx.x * 4 + (threadIdx.x >> 6);
    if (row >= NB * N_OP) return;
    int lane = threadIdx.x & 63;
    const float* h = h_src + (size_t)row * IN_SRC;
    float acc = h[lane] * u[lane] + h[lane + 64] * u[lane + 64];
    acc = wave_sum(acc);
    if (lane == 0) el[row] = acc;
}

// K3: feat_dst[bm,d] = sum_k h_dst[bm,k]*W_dst[k,d]; er[bm] = dot(feat_dst[bm,:], attn_r)
__global__ void fdst_kernel(const float* __restrict__ h_dst, const float* __restrict__ W_dst,
                            const float* __restrict__ attn_r, float* __restrict__ feat_dst,
                            float* __restrict__ er) {
    int bm = blockIdx.x * 4 + (threadIdx.x >> 6);
    if (bm >= NB * N_MA) return;
    int lane = threadIdx.x & 63;
    const float* h = h_dst + (size_t)bm * IN_DST;
    float a0 = 0.f, a1 = 0.f;
    for (int k = 0; k < IN_DST; ++k) {
        float hk = h[k];
        a0 += hk * W_dst[k * DD + lane];
        a1 += hk * W_dst[k * DD + lane + 64];
    }
    feat_dst[(size_t)bm * DD + lane] = a0;
    feat_dst[(size_t)bm * DD + lane + 64] = a1;
    float r = a0 * attn_r[lane] + a1 * attn_r[lane + 64];
    r = wave_sum(r);
    if (lane == 0) er[bm] = r;
}

// K4: per (b,m): masked softmax over o (+kk row), then fused output.
__global__ __launch_bounds__(256) void main_kernel(
    const float* __restrict__ edge_feat, const int* __restrict__ adj,
    const float* __restrict__ h_src, const float* __restrict__ W_src,
    const float* __restrict__ W_edge, const float* __restrict__ el,
    const float* __restrict__ er, const float* __restrict__ feat_dst,
    const float* __restrict__ c_we_p, float* __restrict__ out) {
    __shared__ float p_lds[N_OP];
    __shared__ float s_part[2][IN_SRC];
    __shared__ float redm[4], redz[4], redse[4];
    __shared__ float sM;

    int bm = blockIdx.x;
    int b = bm >> 6, m = bm & 63;
    int tid = threadIdx.x;
    int w = tid >> 6, lane = tid & 63;

    float c_we = c_we_p[0];
    float er_bm = er[bm];
    float ekk = lrelu(2.f * er_bm);

    const float* ef_col = edge_feat + ((size_t)b * N_OP) * N_MA + m;
    const int* adj_col = adj + ((size_t)b * N_OP) * N_MA + m;
    const float* el_b = el + b * N_OP;

    // Pass A: masked max (kk row always included)
    float lmax = ekk;
    for (int o = tid; o < N_OP; o += 256) {
        if (adj_col[(size_t)o * N_MA]) {
            float v = lrelu(el_b[o] + er_bm + ef_col[(size_t)o * N_MA] * c_we);
            lmax = fmaxf(lmax, v);
        }
    }
    lmax = wave_max(lmax);
    if (lane == 0) redm[w] = lmax;
    __syncthreads();
    if (tid == 0) sM = fmaxf(fmaxf(redm[0], redm[1]), fmaxf(redm[2], redm[3]));
    __syncthreads();
    float M = sM;

    // Pass B: p (to LDS), Z, sum_e
    float z = 0.f, se = 0.f;
    for (int o = tid; o < N_OP; o += 256) {
        float p = 0.f;
        if (adj_col[(size_t)o * N_MA]) {
            float ef = ef_col[(size_t)o * N_MA];
            float v = lrelu(el_b[o] + er_bm + ef * c_we);
            p = __expf(v - M);
            z += p;
            se += p * ef;
        }
        p_lds[o] = p;
    }
    z = wave_sum(z);
    se = wave_sum(se);
    if (lane == 0) { redz[w] = z; redse[w] = se; }
    __syncthreads();  // also fences p_lds writes

    float p_kk = __expf(ekk - M);
    float Z = redz[0] + redz[1] + redz[2] + redz[3] + p_kk;
    float SE = redse[0] + redse[1] + redse[2] + redse[3];
    float invZ = 1.f / Z;

    // Pass C: s[i] = sum_o p[o]*h_src[b,o,i]; 2 halves over o parity
    int i = tid & 127;
    int half = tid >> 7;
    const float* hb = h_src + ((size_t)b * N_OP) * IN_SRC;
    float acc = 0.f;
    for (int o = half; o < N_OP; o += 2) acc += p_lds[o] * hb[(size_t)o * IN_SRC + i];
    s_part[half][i] = acc;
    __syncthreads();

    // Pass D: out[d] = sigmoid(W_edge[d]*SE/Z + (s@W_src)[d]/Z + feat_dst[bm,d]*p_kk/Z)
    int d = tid & 127;
    float acc2 = 0.f;
    for (int i2 = half * 64; i2 < half * 64 + 64; ++i2) {
        float si = s_part[0][i2] + s_part[1][i2];
        acc2 += si * W_src[i2 * DD + d];
    }
    p_lds[tid] = acc2;  // reuse as scratch (p no longer needed)
    __syncthreads();
    if (tid < DD) {
        float bsrc = (p_lds[tid] + p_lds[tid + 128]) * invZ;
        float val = W_edge[d] * (SE * invZ) + bsrc + feat_dst[(size_t)bm * DD + d] * (p_kk * invZ);
        out[(size_t)bm * DD + d] = 1.f / (1.f + __expf(-val));
    }
}

extern "C" void kernel_launch(void* const* d_in, const int* in_sizes, int n_in,
                              void* d_out, int out_size, void* d_ws, size_t ws_size,
                              hipStream_t stream) {
    const float* h_src = (const float*)d_in[0];
    const float* h_dst = (const float*)d_in[1];
    const float* edge_feat = (const float*)d_in[2];
    const int* adj = (const int*)d_in[3];
    const float* W_src = (const float*)d_in[4];
    const float* W_dst = (const float*)d_in[5];
    const float* W_edge = (const float*)d_in[6];
    const float* attn_l = (const float*)d_in[7];
    const float* attn_r = (const float*)d_in[8];
    float* out = (float*)d_out;

    float* ws = (float*)d_ws;
    float* u = ws;                 // 128
    float* c_we = ws + 128;        // 1
    float* el = ws + 256;          // 8000
    float* er = ws + 8256;         // 512
    float* feat_dst = ws + 8768;   // 65536

    prep_kernel<<<1, 128, 0, stream>>>(W_src, W_edge, attn_l, u, c_we);
    el_kernel<<<(NB * N_OP + 3) / 4, 256, 0, stream>>>(h_src, u, el);
    fdst_kernel<<<(NB * N_MA + 3) / 4, 256, 0, stream>>>(h_dst, W_dst, attn_r, feat_dst, er);
    main_kernel<<<NB * N_MA, 256, 0, stream>>>(edge_feat, adj, h_src, W_src, W_edge,
                                               el, er, feat_dst, c_we, out);
}

// Round 2
// 30.823 us; speedup vs baseline: 5.3011x; 5.3011x over previous
//
#include <hip/hip_runtime.h>
#include <math.h>

#define NB 8
#define N_OP 1000
#define N_MA 64
#define IN_SRC 128
#define IN_DST 64
#define DD 128
#define NEG_SLOPE 0.2f
#define TILE_O 50
#define NTILE 20   // N_OP / TILE_O

__device__ __forceinline__ float lrelu(float x) { return x >= 0.f ? x : NEG_SLOPE * x; }

__device__ __forceinline__ float wave_sum(float v) {
    for (int off = 32; off; off >>= 1) v += __shfl_xor(v, off, 64);
    return v;
}

// K1: u[i] = sum_d W_src[i,d]*attn_l[d]; c_we = dot(W_edge, attn_l)
__global__ void prep_kernel(const float* __restrict__ W_src, const float* __restrict__ W_edge,
                            const float* __restrict__ attn_l, float* __restrict__ u,
                            float* __restrict__ c_we) {
    int i = threadIdx.x;  // 128 threads
    float acc = 0.f;
    for (int d = 0; d < DD; ++d) acc += W_src[i * DD + d] * attn_l[d];
    u[i] = acc;
    float part = W_edge[i] * attn_l[i];
    part = wave_sum(part);
    __shared__ float red[2];
    if ((i & 63) == 0) red[i >> 6] = part;
    __syncthreads();
    if (i == 0) c_we[0] = red[0] + red[1];
}

// K2 merged: blocks [0,2000): el rows; blocks [2000,2128): feat_dst + er
__global__ __launch_bounds__(256) void elfdst_kernel(
    const float* __restrict__ h_src, const float* __restrict__ u,
    const float* __restrict__ h_dst, const float* __restrict__ W_dst,
    const float* __restrict__ attn_r, float* __restrict__ el,
    float* __restrict__ feat_dst, float* __restrict__ er) {
    int blk = blockIdx.x;
    int lane = threadIdx.x & 63;
    int w = threadIdx.x >> 6;
    if (blk < 2000) {
        int row = blk * 4 + w;   // < 8000 always
        const float* h = h_src + (size_t)row * IN_SRC;
        float acc = h[lane] * u[lane] + h[lane + 64] * u[lane + 64];
        acc = wave_sum(acc);
        if (lane == 0) el[row] = acc;
    } else {
        int bm = (blk - 2000) * 4 + w;  // < 512 always
        const float* h = h_dst + (size_t)bm * IN_DST;
        float a0 = 0.f, a1 = 0.f;
        #pragma unroll 8
        for (int k = 0; k < IN_DST; ++k) {
            float hk = h[k];
            a0 += hk * W_dst[k * DD + lane];
            a1 += hk * W_dst[k * DD + lane + 64];
        }
        feat_dst[(size_t)bm * DD + lane] = a0;
        feat_dst[(size_t)bm * DD + lane + 64] = a1;
        float r = a0 * attn_r[lane] + a1 * attn_r[lane + 64];
        r = wave_sum(r);
        if (lane == 0) er[bm] = r;
    }
}

// K3: per (b, o-tile): p = masked exp (M=0), tile stats, and partial
// contraction S_part[b,ti,m,i] = sum_{o in tile} p[o,m] * h_src[b,o,i]
__global__ __launch_bounds__(256) void ab_kernel(
    const float* __restrict__ edge_feat, const int* __restrict__ adj,
    const float* __restrict__ h_src, const float* __restrict__ el,
    const float* __restrict__ er, const float* __restrict__ c_we_p,
    float* __restrict__ S_part, float* __restrict__ zpart,
    float* __restrict__ separt) {
    __shared__ float P_l[TILE_O][N_MA];    // 12.8 KB
    __shared__ float H_l[TILE_O][DD];      // 25.6 KB
    __shared__ float redz[4][64], redse[4][64];

    int blk = blockIdx.x;               // 0..159
    int b = blk / NTILE, ti = blk % NTILE;
    int o0 = ti * TILE_O;
    int t = threadIdx.x;
    float cwe = c_we_p[0];

    // stage H tile (coalesced float4)
    #pragma unroll
    for (int c = 0; c < 7; ++c) {
        int flat = c * 256 + t;          // float4 slots; need 50*32 = 1600
        int row = flat >> 5, col = (flat & 31) * 4;
        if (row < TILE_O) {
            float4 hv = *reinterpret_cast<const float4*>(
                h_src + ((size_t)(b * N_OP + o0 + row) * DD + col));
            *reinterpret_cast<float4*>(&H_l[row][col]) = hv;
        }
    }

    // phase 1: p + per-tile stats (coalesced adj/ef rows)
    int m = t & 63, og = t >> 6;
    float er_bm = er[b * N_MA + m];
    float z = 0.f, se = 0.f;
    for (int r = og; r < TILE_O; r += 4) {
        int o = o0 + r;
        size_t eidx = (size_t)(b * N_OP + o) * N_MA + m;
        float p = 0.f;
        if (adj[eidx]) {
            float efv = edge_feat[eidx];
            float v = lrelu(el[b * N_OP + o] + er_bm + efv * cwe);
            p = __expf(v);
            z += p;
            se += p * efv;
        }
        P_l[r][m] = p;
    }
    redz[og][m] = z;
    redse[og][m] = se;
    __syncthreads();

    if (t < 64) {
        zpart[ti * 512 + b * N_MA + t] =
            redz[0][t] + redz[1][t] + redz[2][t] + redz[3][t];
    } else if (t < 128) {
        int mm = t - 64;
        separt[ti * 512 + b * N_MA + mm] =
            redse[0][mm] + redse[1][mm] + redse[2][mm] + redse[3][mm];
    }

    // phase 2: partial GEMM  S_part[m][i] = sum_k P_l[k][m] * H_l[k][i]
    int i4 = t & 31;     // i = i4*4 .. +3
    int mg = t >> 3;     // unused name guard
    mg = t >> 5;         // m = mg*8 .. +7
    float acc[8][4];
    #pragma unroll
    for (int a = 0; a < 8; ++a)
        #pragma unroll
        for (int bb = 0; bb < 4; ++bb) acc[a][bb] = 0.f;

    for (int k = 0; k < TILE_O; ++k) {
        float4 hv = *reinterpret_cast<const float4*>(&H_l[k][i4 * 4]);
        float4 pa = *reinterpret_cast<const float4*>(&P_l[k][mg * 8]);
        float4 pb = *reinterpret_cast<const float4*>(&P_l[k][mg * 8 + 4]);
        float hh[4] = {hv.x, hv.y, hv.z, hv.w};
        float pp[8] = {pa.x, pa.y, pa.z, pa.w, pb.x, pb.y, pb.z, pb.w};
        #pragma unroll
        for (int mm = 0; mm < 8; ++mm)
            #pragma unroll
            for (int ii = 0; ii < 4; ++ii)
                acc[mm][ii] += pp[mm] * hh[ii];
    }

    #pragma unroll
    for (int mm = 0; mm < 8; ++mm) {
        size_t off = ((size_t)(b * NTILE + ti) * N_MA + mg * 8 + mm) * DD + i4 * 4;
        float4 v = make_float4(acc[mm][0], acc[mm][1], acc[mm][2], acc[mm][3]);
        *reinterpret_cast<float4*>(S_part + off) = v;
    }
}

// K4: per (b,m): sum partials, matvec with W_src, epilogue sigmoid
__global__ __launch_bounds__(256) void c_kernel(
    const float* __restrict__ S_part, const float* __restrict__ zpart,
    const float* __restrict__ separt, const float* __restrict__ er,
    const float* __restrict__ feat_dst, const float* __restrict__ W_src,
    const float* __restrict__ W_edge, float* __restrict__ out) {
    __shared__ float Sp[2][DD];
    __shared__ float S_l[DD];
    __shared__ float Wp[2][DD];
    __shared__ float sZ, sSE;

    int bm = blockIdx.x;
    int b = bm >> 6, m = bm & 63;
    int t = threadIdx.x;
    int i = t & 127, h = t >> 7;
    int lane = t & 63, w = t >> 6;

    // stats: wave 0 reduces zpart, wave 1 reduces separt
    if (w == 0) {
        float v = (lane < NTILE) ? zpart[lane * 512 + bm] : 0.f;
        v = wave_sum(v);
        if (lane == 0) sZ = v;
    } else if (w == 1) {
        float v = (lane < NTILE) ? separt[lane * 512 + bm] : 0.f;
        v = wave_sum(v);
        if (lane == 0) sSE = v;
    }

    // partial sums of S over tiles (coalesced)
    float ps = 0.f;
    #pragma unroll
    for (int q = 0; q < NTILE / 2; ++q) {
        int ti = h * (NTILE / 2) + q;
        ps += S_part[((size_t)(b * NTILE + ti) * N_MA + m) * DD + i];
    }
    Sp[h][i] = ps;
    __syncthreads();
    if (t < DD) S_l[t] = Sp[0][t] + Sp[1][t];
    __syncthreads();

    // matvec: bsrc[d] = sum_i S_l[i] * W_src[i,d]
    int d = i;
    float acc = 0.f;
    #pragma unroll 8
    for (int q = 0; q < 64; ++q) {
        int ii = h * 64 + q;
        acc += S_l[ii] * W_src[ii * DD + d];
    }
    Wp[h][d] = acc;
    __syncthreads();

    if (t < DD) {
        float er_bm = er[bm];
        float p_kk = __expf(lrelu(2.f * er_bm));
        float Z = sZ + p_kk;
        float invZ = 1.f / Z;
        float bsrc = (Wp[0][d] + Wp[1][d]) * invZ;
        float val = W_edge[d] * (sSE * invZ) + bsrc +
                    feat_dst[(size_t)bm * DD + d] * (p_kk * invZ);
        out[(size_t)bm * DD + d] = 1.f / (1.f + __expf(-val));
    }
}

extern "C" void kernel_launch(void* const* d_in, const int* in_sizes, int n_in,
                              void* d_out, int out_size, void* d_ws, size_t ws_size,
                              hipStream_t stream) {
    const float* h_src = (const float*)d_in[0];
    const float* h_dst = (const float*)d_in[1];
    const float* edge_feat = (const float*)d_in[2];
    const int* adj = (const int*)d_in[3];
    const float* W_src = (const float*)d_in[4];
    const float* W_dst = (const float*)d_in[5];
    const float* W_edge = (const float*)d_in[6];
    const float* attn_l = (const float*)d_in[7];
    const float* attn_r = (const float*)d_in[8];
    float* out = (float*)d_out;

    float* ws = (float*)d_ws;
    float* u = ws;                     // 128
    float* c_we = ws + 128;            // 1 (pad to 256)
    float* el = ws + 256;              // 8000
    float* er = ws + 8256;             // 512
    float* feat_dst = ws + 8768;       // 65536
    float* zpart = ws + 74304;         // 20*512 = 10240
    float* separt = ws + 84544;        // 10240
    float* S_part = ws + 94784;        // 8*20*64*128 = 1310720

    prep_kernel<<<1, 128, 0, stream>>>(W_src, W_edge, attn_l, u, c_we);
    elfdst_kernel<<<2128, 256, 0, stream>>>(h_src, u, h_dst, W_dst, attn_r,
                                            el, feat_dst, er);
    ab_kernel<<<NB * NTILE, 256, 0, stream>>>(edge_feat, adj, h_src, el, er,
                                              c_we, S_part, zpart, separt);
    c_kernel<<<NB * N_MA, 256, 0, stream>>>(S_part, zpart, separt, er,
                                            feat_dst, W_src, W_edge, out);
}